// Round 2
// baseline (142.616 us; speedup 1.0000x reference)
//
#include <hip/hip_runtime.h>

// N=512, D=512 pairwise scorer, all f32.
// left = E@W1[:D]; right = E@W1[D:]+b1; h = left[i]+right[j]; LN(D); GELU; @W2+b2; sigmoid.
// LN stats decompose: var = var_l[i]+var_r[j]+2*cov(i,j), cov = (1/D) lc@rc^T (centered).
// Never materialize [N,N,D]. Upper-triangle 16x16 pair tiles, mirrored store.

#define N_ 512
#define D_ 512

// ---------------- K1: left/right GEMMs ----------------
__global__ __launch_bounds__(256) void k_gemm(const float* __restrict__ E,
                                              const float* __restrict__ W1,
                                              const float* __restrict__ b1,
                                              float* __restrict__ W /* [1024][512] */) {
    __shared__ float e[16][516];  // 516 mod 32 = 4: 2-row stride -> 8 -> free 2-way
    const int t = threadIdx.x;
    const int cc = (blockIdx.x & 7) * 128;     // combined col base (0..896)
    const int r0 = (blockIdx.x >> 3) * 16;
    const int half = cc >> 9;
    const int c = (cc & 511) + (t & 31) * 4;
    const int rp = (t >> 5) * 2;

    for (int x = t; x < 16 * 128; x += 256) {
        int r = x >> 7, c4 = (x & 127) << 2;
        *(float4*)&e[r][c4] = *(const float4*)&E[(r0 + r) * D_ + c4];
    }
    __syncthreads();

    const float* __restrict__ wp = W1 + (half << 18) + c;
    float4 a0 = {0.f, 0.f, 0.f, 0.f}, a1 = {0.f, 0.f, 0.f, 0.f};
#pragma unroll 4
    for (int k = 0; k < D_; k += 4) {
        float4 e0 = *(float4*)&e[rp][k];
        float4 e1 = *(float4*)&e[rp + 1][k];
        float4 wa = *(const float4*)(wp + ((k + 0) << 9));
        float4 wb = *(const float4*)(wp + ((k + 1) << 9));
        float4 wc = *(const float4*)(wp + ((k + 2) << 9));
        float4 wd = *(const float4*)(wp + ((k + 3) << 9));
        a0.x = fmaf(e0.x, wa.x, a0.x); a0.y = fmaf(e0.x, wa.y, a0.y);
        a0.z = fmaf(e0.x, wa.z, a0.z); a0.w = fmaf(e0.x, wa.w, a0.w);
        a1.x = fmaf(e1.x, wa.x, a1.x); a1.y = fmaf(e1.x, wa.y, a1.y);
        a1.z = fmaf(e1.x, wa.z, a1.z); a1.w = fmaf(e1.x, wa.w, a1.w);
        a0.x = fmaf(e0.y, wb.x, a0.x); a0.y = fmaf(e0.y, wb.y, a0.y);
        a0.z = fmaf(e0.y, wb.z, a0.z); a0.w = fmaf(e0.y, wb.w, a0.w);
        a1.x = fmaf(e1.y, wb.x, a1.x); a1.y = fmaf(e1.y, wb.y, a1.y);
        a1.z = fmaf(e1.y, wb.z, a1.z); a1.w = fmaf(e1.y, wb.w, a1.w);
        a0.x = fmaf(e0.z, wc.x, a0.x); a0.y = fmaf(e0.z, wc.y, a0.y);
        a0.z = fmaf(e0.z, wc.z, a0.z); a0.w = fmaf(e0.z, wc.w, a0.w);
        a1.x = fmaf(e1.z, wc.x, a1.x); a1.y = fmaf(e1.z, wc.y, a1.y);
        a1.z = fmaf(e1.z, wc.z, a1.z); a1.w = fmaf(e1.z, wc.w, a1.w);
        a0.x = fmaf(e0.w, wd.x, a0.x); a0.y = fmaf(e0.w, wd.y, a0.y);
        a0.z = fmaf(e0.w, wd.z, a0.z); a0.w = fmaf(e0.w, wd.w, a0.w);
        a1.x = fmaf(e1.w, wd.x, a1.x); a1.y = fmaf(e1.w, wd.y, a1.y);
        a1.z = fmaf(e1.w, wd.z, a1.z); a1.w = fmaf(e1.w, wd.w, a1.w);
    }
    if (half) {
        float4 bb = *(const float4*)(b1 + c);
        a0.x += bb.x; a0.y += bb.y; a0.z += bb.z; a0.w += bb.w;
        a1.x += bb.x; a1.y += bb.y; a1.z += bb.z; a1.w += bb.w;
    }
    *(float4*)(W + ((half << 9) + r0 + rp) * D_ + c) = a0;
    *(float4*)(W + ((half << 9) + r0 + rp + 1) * D_ + c) = a1;
}

// ---------------- K2: center rows, per-row variance ----------------
// Wave-per-row: 256 blocks x 4 waves, shuffle-only reduce, zero barriers.
__global__ __launch_bounds__(256) void k_center(float* __restrict__ W,
                                                float* __restrict__ var) {
    const int t = threadIdx.x;
    const int lane = t & 63;
    const int r = (blockIdx.x << 2) + (t >> 6);
    float* p = W + r * D_;
    float4 v0 = *(float4*)&p[lane << 2];
    float4 v1 = *(float4*)&p[256 + (lane << 2)];
    float s = (v0.x + v0.y) + (v0.z + v0.w) + (v1.x + v1.y) + (v1.z + v1.w);
#pragma unroll
    for (int off = 32; off > 0; off >>= 1) s += __shfl_xor(s, off, 64);
    const float mean = s * (1.f / D_);
    v0.x -= mean; v0.y -= mean; v0.z -= mean; v0.w -= mean;
    v1.x -= mean; v1.y -= mean; v1.z -= mean; v1.w -= mean;
    float ss = v0.x * v0.x + v0.y * v0.y + v0.z * v0.z + v0.w * v0.w +
               v1.x * v1.x + v1.y * v1.y + v1.z * v1.z + v1.w * v1.w;
#pragma unroll
    for (int off = 32; off > 0; off >>= 1) ss += __shfl_xor(ss, off, 64);
    *(float4*)&p[lane << 2] = v0;
    *(float4*)&p[256 + (lane << 2)] = v1;
    if (lane == 0) var[r] = ss * (1.f / D_);
}

// ---------------- K3: fused cov -> rstd -> gelu-dot -> sigmoid ----------------
// 528 blocks = upper-triangle 16x16 pair tiles. 512 thr (8 waves) = 32 pair-
// threads (pt: 2x4 pair block) x 16 k-slices (ks, low 4 lane bits). Full
// 16x512 l/r tiles resident in LDS (66KB -> 2 blocks/CU, 16 waves/CU). ONE
// barrier; k-slice reduce = 4-step shfl_xor butterfly.
// SPILL-PROOF: all accumulators are NAMED SCALARS (round-1's cv[8]/ac[8]/
// float&-alias arrays were demoted to scratch: WRITE_SIZE 1MB->37MB, VGPR 64).

// gelu_tanh(x) = x * sigmoid(1.5957691*(x + 0.044715 x^3))
// q = log2(exp(-2y)) = x*(A*x^2+B), B = -2*log2e*0.79788456, A = B*0.044715
#define GELU1(L, R, G, BE, WC, RST, ACC)                                      \
    do {                                                                      \
        float s_ = (L) + (R);                                                 \
        float x_ = fmaf(s_ * (RST), (G), (BE));                               \
        float q_ = x_ * fmaf(-0.10294340f, x_ * x_, -2.30220935f);            \
        float e_ = __builtin_amdgcn_exp2f(q_);                                \
        float ge_ = x_ * __builtin_amdgcn_rcpf(1.f + e_);                     \
        ACC = fmaf(ge_, (WC), ACC);                                           \
    } while (0)

#define GELU4(LQ, RQ, RST, ACC)                                               \
    do {                                                                      \
        GELU1(LQ.x, RQ.x, g4.x, be4.x, w4.x, RST, ACC);                       \
        GELU1(LQ.y, RQ.y, g4.y, be4.y, w4.y, RST, ACC);                       \
        GELU1(LQ.z, RQ.z, g4.z, be4.z, w4.z, RST, ACC);                       \
        GELU1(LQ.w, RQ.w, g4.w, be4.w, w4.w, RST, ACC);                       \
    } while (0)

#define DOT4(LQ, RQ, ACC)                                                     \
    ACC += LQ.x * RQ.x + LQ.y * RQ.y + LQ.z * RQ.z + LQ.w * RQ.w

#define BFLY(V)                                                               \
    do {                                                                      \
        V += __shfl_xor(V, 1, 64);                                            \
        V += __shfl_xor(V, 2, 64);                                            \
        V += __shfl_xor(V, 4, 64);                                            \
        V += __shfl_xor(V, 8, 64);                                            \
    } while (0)

__global__ __launch_bounds__(512, 4) void k_pair(const float* __restrict__ W,
                                                 const float* __restrict__ var,
                                                 const float* __restrict__ gf,
                                                 const float* __restrict__ bef,
                                                 const float* __restrict__ wf,
                                                 const float* __restrict__ b2f,
                                                 float* __restrict__ out) {
    __shared__ float ls[16][516];   // 516 mod 32 = 4 -> reads spread 8 bank-quads
    __shared__ float rs[16][516];

    // decode upper-triangle tile index b -> (I, J), I<=J, 32 tile-rows
    const int b = blockIdx.x;
    int I = (int)((65.0f - sqrtf(4225.0f - 8.0f * (float)b)) * 0.5f);
    if (I < 0) I = 0;
    if (I > 31) I = 31;
#define S_(i) (32 * (i) - ((i) * ((i)-1)) / 2)
    while (S_(I) > b) --I;
    while (S_(I + 1) <= b) ++I;
    const int J = I + (b - S_(I));
#undef S_

    const int t = threadIdx.x;
    const int ks = t & 15;          // k-slice: lane bits 0..3 -> shfl-reducible
    const int pt = t >> 4;          // 0..31 pair-threads
    const int i2 = (pt & 7) * 2, j4 = (pt >> 3) * 4;
    const int Ibase = I * 16, Jbase = N_ + J * 16;

    // ---- stage full tiles once (4 iters, coalesced 1KB/row chunks) ----
    for (int x = t; x < 16 * 128; x += 512) {
        int r = x >> 7, c4 = (x & 127) << 2;
        *(float4*)&ls[r][c4] = *(const float4*)&W[(Ibase + r) * D_ + c4];
        *(float4*)&rs[r][c4] = *(const float4*)&W[(Jbase + r) * D_ + c4];
    }
    __syncthreads();   // the only barrier in this kernel

    // ---- pass A: cov (2 l-rows x 4 r-rows, named scalar chains) ----
    float cv0 = 0.f, cv1 = 0.f, cv2 = 0.f, cv3 = 0.f;
    float cv4 = 0.f, cv5 = 0.f, cv6 = 0.f, cv7 = 0.f;
    for (int it = 0; it < 8; ++it) {
        const int kq = (it * 16 + ks) * 4;
        float4 la = *(float4*)&ls[i2][kq];
        float4 lb = *(float4*)&ls[i2 + 1][kq];
        float4 ra = *(float4*)&rs[j4][kq];
        float4 rb = *(float4*)&rs[j4 + 1][kq];
        float4 rc = *(float4*)&rs[j4 + 2][kq];
        float4 rd = *(float4*)&rs[j4 + 3][kq];
        DOT4(la, ra, cv0); DOT4(la, rb, cv1); DOT4(la, rc, cv2); DOT4(la, rd, cv3);
        DOT4(lb, ra, cv4); DOT4(lb, rb, cv5); DOT4(lb, rc, cv6); DOT4(lb, rd, cv7);
    }
    BFLY(cv0); BFLY(cv1); BFLY(cv2); BFLY(cv3);
    BFLY(cv4); BFLY(cv5); BFLY(cv6); BFLY(cv7);

    // ---- rstd in-register (no LDS, no barrier) ----
    const float vl0 = var[Ibase + i2], vl1 = var[Ibase + i2 + 1];
    const float vr0 = var[Jbase + j4], vr1 = var[Jbase + j4 + 1];
    const float vr2 = var[Jbase + j4 + 2], vr3 = var[Jbase + j4 + 3];
    const float rst0 = rsqrtf(vl0 + vr0 + cv0 * (2.f / D_) + 1e-5f);
    const float rst1 = rsqrtf(vl0 + vr1 + cv1 * (2.f / D_) + 1e-5f);
    const float rst2 = rsqrtf(vl0 + vr2 + cv2 * (2.f / D_) + 1e-5f);
    const float rst3 = rsqrtf(vl0 + vr3 + cv3 * (2.f / D_) + 1e-5f);
    const float rst4 = rsqrtf(vl1 + vr0 + cv4 * (2.f / D_) + 1e-5f);
    const float rst5 = rsqrtf(vl1 + vr1 + cv5 * (2.f / D_) + 1e-5f);
    const float rst6 = rsqrtf(vl1 + vr2 + cv6 * (2.f / D_) + 1e-5f);
    const float rst7 = rsqrtf(vl1 + vr3 + cv7 * (2.f / D_) + 1e-5f);

    // ---- pass B: gelu dot over the same resident tiles ----
    float ac0 = 0.f, ac1 = 0.f, ac2 = 0.f, ac3 = 0.f;
    float ac4 = 0.f, ac5 = 0.f, ac6 = 0.f, ac7 = 0.f;
    for (int it = 0; it < 8; ++it) {
        const int kq = (it * 16 + ks) * 4;
        float4 g4 = *(const float4*)&gf[kq];
        float4 be4 = *(const float4*)&bef[kq];
        float4 w4 = *(const float4*)&wf[kq];
        float4 la = *(float4*)&ls[i2][kq];
        float4 lb = *(float4*)&ls[i2 + 1][kq];
        float4 ra = *(float4*)&rs[j4][kq];
        float4 rb = *(float4*)&rs[j4 + 1][kq];
        float4 rc = *(float4*)&rs[j4 + 2][kq];
        float4 rd = *(float4*)&rs[j4 + 3][kq];
        GELU4(la, ra, rst0, ac0); GELU4(la, rb, rst1, ac1);
        GELU4(la, rc, rst2, ac2); GELU4(la, rd, rst3, ac3);
        GELU4(lb, ra, rst4, ac4); GELU4(lb, rb, rst5, ac5);
        GELU4(lb, rc, rst6, ac6); GELU4(lb, rd, rst7, ac7);
    }
    BFLY(ac0); BFLY(ac1); BFLY(ac2); BFLY(ac3);
    BFLY(ac4); BFLY(ac5); BFLY(ac6); BFLY(ac7);

    // ---- sigmoid + mirrored store (ks==0 lane of each pair-thread) ----
    if (ks == 0) {
        const float bb = b2f[0];
        const float z0 = __builtin_amdgcn_rcpf(
            1.f + __builtin_amdgcn_exp2f(-1.44269504f * (ac0 + bb)));
        const float z1 = __builtin_amdgcn_rcpf(
            1.f + __builtin_amdgcn_exp2f(-1.44269504f * (ac1 + bb)));
        const float z2 = __builtin_amdgcn_rcpf(
            1.f + __builtin_amdgcn_exp2f(-1.44269504f * (ac2 + bb)));
        const float z3 = __builtin_amdgcn_rcpf(
            1.f + __builtin_amdgcn_exp2f(-1.44269504f * (ac3 + bb)));
        const float z4 = __builtin_amdgcn_rcpf(
            1.f + __builtin_amdgcn_exp2f(-1.44269504f * (ac4 + bb)));
        const float z5 = __builtin_amdgcn_rcpf(
            1.f + __builtin_amdgcn_exp2f(-1.44269504f * (ac5 + bb)));
        const float z6 = __builtin_amdgcn_rcpf(
            1.f + __builtin_amdgcn_exp2f(-1.44269504f * (ac6 + bb)));
        const float z7 = __builtin_amdgcn_rcpf(
            1.f + __builtin_amdgcn_exp2f(-1.44269504f * (ac7 + bb)));
        const int gi0 = Ibase + i2;
        const int gj0 = (Jbase - N_) + j4;
        if (I < J) {
            float4 o0 = {z0, z1, z2, z3};
            float4 o1 = {z4, z5, z6, z7};
            *(float4*)&out[gi0 * N_ + gj0] = o0;
            *(float4*)&out[(gi0 + 1) * N_ + gj0] = o1;
            out[gj0 * N_ + gi0] = z0;       out[gj0 * N_ + gi0 + 1] = z4;
            out[(gj0 + 1) * N_ + gi0] = z1; out[(gj0 + 1) * N_ + gi0 + 1] = z5;
            out[(gj0 + 2) * N_ + gi0] = z2; out[(gj0 + 2) * N_ + gi0 + 1] = z6;
            out[(gj0 + 3) * N_ + gi0] = z3; out[(gj0 + 3) * N_ + gi0 + 1] = z7;
        } else {  // diagonal tile: only pairs gi<=gj are valid
            if (gi0 <= gj0)     { out[gi0 * N_ + gj0] = z0;       out[gj0 * N_ + gi0] = z0; }
            if (gi0 <= gj0 + 1) { out[gi0 * N_ + gj0 + 1] = z1;   out[(gj0 + 1) * N_ + gi0] = z1; }
            if (gi0 <= gj0 + 2) { out[gi0 * N_ + gj0 + 2] = z2;   out[(gj0 + 2) * N_ + gi0] = z2; }
            if (gi0 <= gj0 + 3) { out[gi0 * N_ + gj0 + 3] = z3;   out[(gj0 + 3) * N_ + gi0] = z3; }
            if (gi0 + 1 <= gj0)     { out[(gi0 + 1) * N_ + gj0] = z4;     out[gj0 * N_ + gi0 + 1] = z4; }
            if (gi0 + 1 <= gj0 + 1) { out[(gi0 + 1) * N_ + gj0 + 1] = z5; out[(gj0 + 1) * N_ + gi0 + 1] = z5; }
            if (gi0 + 1 <= gj0 + 2) { out[(gi0 + 1) * N_ + gj0 + 2] = z6; out[(gj0 + 2) * N_ + gi0 + 1] = z6; }
            if (gi0 + 1 <= gj0 + 3) { out[(gi0 + 1) * N_ + gj0 + 3] = z7; out[(gj0 + 3) * N_ + gi0 + 1] = z7; }
        }
    }
}

extern "C" void kernel_launch(void* const* d_in, const int* in_sizes, int n_in,
                              void* d_out, int out_size, void* d_ws, size_t ws_size,
                              hipStream_t stream) {
    const float* E     = (const float*)d_in[0];
    const float* W1    = (const float*)d_in[1];
    const float* b1    = (const float*)d_in[2];
    const float* gamma = (const float*)d_in[3];
    const float* beta  = (const float*)d_in[4];
    const float* w2    = (const float*)d_in[5];
    const float* b2    = (const float*)d_in[6];
    float* out = (float*)d_out;

    float* F    = (float*)d_ws;
    float* lcrc = F;                  // [1024][512]: rows 0..511 lc, 512..1023 rc(+b1)
    float* var  = F + 1024 * 512;     // [1024]

    k_gemm<<<256, 256, 0, stream>>>(E, W1, b1, lcrc);
    k_center<<<256, 256, 0, stream>>>(lcrc, var);
    k_pair<<<528, 512, 0, stream>>>(lcrc, var, gamma, beta, w2, b2, out);
}